// Round 8
// baseline (40.282 us; speedup 1.0000x reference)
//
#include <hip/hip_runtime.h>

#define NDENSE 13
#define NSPARSE 26
#define ROW_F4 156     // fp32 v row = 156 float4
#define BATCH 4096
#define VROWS 26013
#define ROW_U32 160    // padded f8 row = 160 uint32 = 640 B
#define ROW_U4  40     // = 40 uint4
#define NSLICE 10      // 64 B f8 slices per row
#define SRPB   64      // rows per block in sq kernel

// ---------------- fp8 e4m3 (OCP) encode/decode --------------------------
#if defined(__has_builtin)
#if __has_builtin(__builtin_amdgcn_cvt_pk_fp8_f32) && __has_builtin(__builtin_amdgcn_cvt_pk_f32_fp8)
#define FP8_HW 1
#endif
#endif

typedef float f32x2 __attribute__((ext_vector_type(2)));

__device__ inline unsigned enc1(float f) {
    unsigned u = __float_as_uint(f);
    unsigned s = (u >> 24) & 0x80u;
    unsigned a = u & 0x7fffffffu;
    if (a >= 0x3c800000u) {                       // |f| >= 2^-6 : normal
        unsigned r = a + 0x7ffffu + ((a >> 20) & 1u);   // RNE at bit 20
        return s | ((r - (120u << 23)) >> 20);
    }
    return s | (unsigned)__float2uint_rn(__uint_as_float(a) * 512.f); // subnormal
}
__device__ inline float dec1(unsigned b) {
    unsigned em = b & 0x7fu;
    float mag = (em >= 8u) ? __uint_as_float((em << 20) + (120u << 23))
                           : (float)em * 0x1p-9f;
    return (b & 0x80u) ? -mag : mag;
}
__device__ inline unsigned enc4(float4 x) {
#ifdef FP8_HW
    int pk = 0;
    pk = __builtin_amdgcn_cvt_pk_fp8_f32(x.x, x.y, pk, false);
    pk = __builtin_amdgcn_cvt_pk_fp8_f32(x.z, x.w, pk, true);
    return (unsigned)pk;
#else
    return enc1(x.x) | (enc1(x.y) << 8) | (enc1(x.z) << 16) | (enc1(x.w) << 24);
#endif
}
__device__ inline float4 dec4(unsigned p) {
#ifdef FP8_HW
    f32x2 lo = __builtin_amdgcn_cvt_pk_f32_fp8((int)p, false);
    f32x2 hi = __builtin_amdgcn_cvt_pk_f32_fp8((int)p, true);
    return make_float4(lo.x, lo.y, hi.x, hi.y);
#else
    return make_float4(dec1(p & 0xffu), dec1((p >> 8) & 0xffu),
                       dec1((p >> 16) & 0xffu), dec1((p >> 24) & 0xffu));
#endif
}

// ---------------------------------------------------------------------------
// Prep: one pass over v (65 MB). Emits (a) f8 copy, rows padded to 640 B,
// (b) u[r][16] = sum_f v[r,f,:] (exact first-moment table), (c) nrmc[r] =
// ||v_r||^2 - ||f8(v_r)||^2 (exact diagonal correction for sq).
__global__ __launch_bounds__(256) void ffm_prep(
    const float4* __restrict__ v4, unsigned* __restrict__ vh,
    float* __restrict__ u, float* __restrict__ nrmc)
{
    const int wv = threadIdx.x >> 6, lane = threadIdx.x & 63;
    const int row = blockIdx.x * 4 + wv;
    if (row >= VROWS) return;

    float4 us = make_float4(0.f, 0.f, 0.f, 0.f);
    float  nc = 0.f;
#pragma unroll
    for (int p = 0; p < 3; ++p) {
        const int e4 = lane + 64 * p;
        if (e4 < ROW_F4) {
            const float4 x = v4[(size_t)row * ROW_F4 + e4];
            const unsigned pk = enc4(x);
            const float4 xh = dec4(pk);
            vh[(size_t)row * ROW_U32 + e4] = pk;
            us.x += x.x; us.y += x.y; us.z += x.z; us.w += x.w;
            nc += (x.x*x.x - xh.x*xh.x) + (x.y*x.y - xh.y*xh.y)
                + (x.z*x.z - xh.z*xh.z) + (x.w*x.w - xh.w*xh.w);
        } else if (e4 < ROW_U32) {
            vh[(size_t)row * ROW_U32 + e4] = 0u;   // pad = 0
        }
    }
    // u: lane&3 is the k-group (value index = 4*e4+q, k = 4*(e4&3)+q)
#pragma unroll
    for (int m = 4; m <= 32; m <<= 1) {
        us.x += __shfl_xor(us.x, m); us.y += __shfl_xor(us.y, m);
        us.z += __shfl_xor(us.z, m); us.w += __shfl_xor(us.w, m);
    }
    if (lane < 4)
        ((float4*)(u + (size_t)row * 16))[lane] = us;
#pragma unroll
    for (int m = 1; m <= 32; m <<= 1) nc += __shfl_xor(nc, m);
    if (lane == 0) nrmc[row] = nc;
}

// ---------------------------------------------------------------------------
// sq kernel: XCD-pinned 64B f8 slices (WS 1.66 MB/slice, <=3.3 MB straddling
// -> L2-resident). Slice s covers fields 4s..4s+3. Lane owns (row, field):
// its 16 B gather = one complete field vector. Dense part exact from LDS.
// Writes per-slice sq partials only (no field_f materialization).
__global__ __launch_bounds__(256) void ffm_sq(
    const float* __restrict__ dense,
    const int*   __restrict__ sparse,
    const float* __restrict__ v,
    const uint4* __restrict__ vh4,
    float*       __restrict__ part)     // [10][4096]
{
    const int x = blockIdx.x & 7;
    const int i = blockIdx.x >> 3;       // 0..79 per XCD
    const int fid = x * 80 + i;          // 0..639
    const int slice = fid >> 6, chunk = fid & 63;
    const int row0 = chunk * SRPB;

    __shared__ int    vrow_s[SRPB * NSPARSE];  // 6656 B
    __shared__ float  dsh   [SRPB * NDENSE];   // 3328 B
    __shared__ float4 vsh4  [NDENSE * 16];     // 3328 B fp32 dense v-slice

    const int t = threadIdx.x;
    for (int q = t; q < SRPB * NSPARSE; q += 256) {
        const int r = q / NSPARSE, j = q % NSPARSE;
        vrow_s[q] = sparse[(row0 + r) * NSPARSE + j] + NDENSE + 1000 * j;
    }
    for (int q = t; q < SRPB * NDENSE; q += 256)
        dsh[q] = dense[row0 * NDENSE + q];
    for (int q = t; q < NDENSE * 64; q += 256) {
        const int d = q >> 6, h = q & 63, col = slice * 64 + h;
        ((float*)vsh4)[q] = (col < 624) ? v[(size_t)d * 624 + col] : 0.f;
    }
    __syncthreads();

    const int lane = t & 63, wv = t >> 6;
    const int rl = wv * 16 + (lane >> 2);   // local row 0..63
    const int c  = lane & 3;                // field within slice

    float4 av0 = make_float4(0.f,0.f,0.f,0.f), av1 = av0, av2 = av0, av3 = av0;

    // dense contribution (exact fp32)
#pragma unroll
    for (int d = 0; d < NDENSE; ++d) {
        const float wg = dsh[rl * NDENSE + d];
        const float4 b0 = vsh4[d * 16 + c * 4 + 0];
        const float4 b1 = vsh4[d * 16 + c * 4 + 1];
        const float4 b2 = vsh4[d * 16 + c * 4 + 2];
        const float4 b3 = vsh4[d * 16 + c * 4 + 3];
        av0.x += wg*b0.x; av0.y += wg*b0.y; av0.z += wg*b0.z; av0.w += wg*b0.w;
        av1.x += wg*b1.x; av1.y += wg*b1.y; av1.z += wg*b1.z; av1.w += wg*b1.w;
        av2.x += wg*b2.x; av2.y += wg*b2.y; av2.z += wg*b2.z; av2.w += wg*b2.w;
        av3.x += wg*b3.x; av3.y += wg*b3.y; av3.z += wg*b3.z; av3.w += wg*b3.w;
    }

    // 26 f8 gathers: 16 B each = one field vector
#pragma unroll
    for (int j = 0; j < NSPARSE; ++j) {
        const unsigned r = (unsigned)vrow_s[rl * NSPARSE + j];
        const uint4 g = vh4[(size_t)r * ROW_U4 + slice * 4 + c];
        float4 d0 = dec4(g.x), d1 = dec4(g.y), d2 = dec4(g.z), d3 = dec4(g.w);
        av0.x += d0.x; av0.y += d0.y; av0.z += d0.z; av0.w += d0.w;
        av1.x += d1.x; av1.y += d1.y; av1.z += d1.z; av1.w += d1.w;
        av2.x += d2.x; av2.y += d2.y; av2.z += d2.z; av2.w += d2.w;
        av3.x += d3.x; av3.y += d3.y; av3.z += d3.z; av3.w += d3.w;
    }

    float sq = av0.x*av0.x + av0.y*av0.y + av0.z*av0.z + av0.w*av0.w
             + av1.x*av1.x + av1.y*av1.y + av1.z*av1.z + av1.w*av1.w
             + av2.x*av2.x + av2.y*av2.y + av2.z*av2.z + av2.w*av2.w
             + av3.x*av3.x + av3.y*av3.y + av3.z*av3.z + av3.w*av3.w;
    sq += __shfl_xor(sq, 1);
    sq += __shfl_xor(sq, 2);
    if (c == 0) part[slice * BATCH + row0 + rl] = sq;
}

// ---------------------------------------------------------------------------
// Final: exact s from u-table gathers, sq = partials + diagonal correction,
// plus first order.
__global__ __launch_bounds__(256) void ffm_out(
    const float* __restrict__ dense,
    const int*   __restrict__ sparse,
    const float* __restrict__ w0,
    const float* __restrict__ w,
    const float* __restrict__ u,
    const float* __restrict__ nrmc,
    const float* __restrict__ part,
    float*       __restrict__ out)
{
    const int wave = threadIdx.x >> 6;
    const int lane = threadIdx.x & 63;
    const int b = blockIdx.x * 4 + wave;
    const int g = lane >> 4, k = lane & 15;

    float s = 0.f;
    for (int j = g; j < NSPARSE; j += 4) {
        const int r = sparse[b * NSPARSE + j] + NDENSE + 1000 * j;
        s += u[(size_t)r * 16 + k];
    }
    for (int d = g; d < NDENSE; d += 4)
        s += dense[b * NDENSE + d] * u[(size_t)d * 16 + k];
    s += __shfl_xor(s, 16);
    s += __shfl_xor(s, 32);          // all lanes: total s[k] for k=lane&15

    float s2 = s * s;
    s2 += __shfl_xor(s2, 1);
    s2 += __shfl_xor(s2, 2);
    s2 += __shfl_xor(s2, 4);
    s2 += __shfl_xor(s2, 8);         // all lanes: ||s||^2

    float red = 0.f, fo = 0.f;
    if (lane < NSLICE) red = part[lane * BATCH + b];
    if (lane < NSPARSE) {
        const int r = sparse[b * NSPARSE + lane] + NDENSE + 1000 * lane;
        fo = w[r];
        red += nrmc[r];              // diagonal correction
    }
    if (lane < NDENSE) fo += dense[b * NDENSE + lane] * w[lane];
#pragma unroll
    for (int m = 1; m <= 32; m <<= 1) {
        fo  += __shfl_xor(fo, m);
        red += __shfl_xor(red, m);
    }
    if (lane == 0) out[b] = w0[0] + fo + 0.5f * (s2 - red);
}

// ---------------------------------------------------------------------------
// Fallback: R1 fused kernel (only if ws too small).
__global__ __launch_bounds__(256) void ffm_fused(
    const float* __restrict__ dense, const int* __restrict__ sparse,
    const float* __restrict__ w0, const float* __restrict__ w,
    const float4* __restrict__ v4, float* __restrict__ out)
{
    const int wave = threadIdx.x >> 6;
    const int lane = threadIdx.x & 63;
    const int b = blockIdx.x * 4 + wave;

    float dv[NDENSE];
#pragma unroll
    for (int d = 0; d < NDENSE; ++d) dv[d] = dense[b * NDENSE + d];
    int myidx = 0;
    if (lane < NSPARSE) myidx = sparse[b * NSPARSE + lane] + NDENSE + 1000 * lane;

    float4 s = make_float4(0.f, 0.f, 0.f, 0.f);
    float  sq = 0.f;
#pragma unroll
    for (int p = 0; p < 3; ++p) {
        const int e4 = lane + 64 * p;
        if (e4 < ROW_F4) {
            float4 acc = make_float4(0.f, 0.f, 0.f, 0.f);
#pragma unroll
            for (int d = 0; d < NDENSE; ++d) {
                const float4 vv = v4[d * ROW_F4 + e4];
                acc.x += dv[d]*vv.x; acc.y += dv[d]*vv.y;
                acc.z += dv[d]*vv.z; acc.w += dv[d]*vv.w;
            }
#pragma unroll
            for (int j = 0; j < NSPARSE; ++j) {
                const int ij = __shfl(myidx, j);
                const float4 vv = v4[(size_t)ij * ROW_F4 + e4];
                acc.x += vv.x; acc.y += vv.y; acc.z += vv.z; acc.w += vv.w;
            }
            s.x += acc.x; s.y += acc.y; s.z += acc.z; s.w += acc.w;
            sq  += acc.x*acc.x + acc.y*acc.y + acc.z*acc.z + acc.w*acc.w;
        }
    }
#pragma unroll
    for (int m = 4; m <= 32; m <<= 1) {
        s.x += __shfl_xor(s.x, m); s.y += __shfl_xor(s.y, m);
        s.z += __shfl_xor(s.z, m); s.w += __shfl_xor(s.w, m);
    }
    float s2 = s.x*s.x + s.y*s.y + s.z*s.z + s.w*s.w;
    s2 += __shfl_xor(s2, 1);
    s2 += __shfl_xor(s2, 2);
#pragma unroll
    for (int m = 1; m <= 32; m <<= 1) sq += __shfl_xor(sq, m);
    float fo = 0.f;
    if (lane < NSPARSE) fo = w[myidx];
    if (lane < NDENSE)  fo += dense[b * NDENSE + lane] * w[lane];
#pragma unroll
    for (int m = 1; m <= 32; m <<= 1) fo += __shfl_xor(fo, m);
    if (lane == 0) out[b] = w0[0] + fo + 0.5f * (s2 - sq);
}

extern "C" void kernel_launch(void* const* d_in, const int* in_sizes, int n_in,
                              void* d_out, int out_size, void* d_ws, size_t ws_size,
                              hipStream_t stream) {
    const float*  dense  = (const float*)d_in[0];
    const int*    sparse = (const int*)d_in[1];
    const float*  w0     = (const float*)d_in[2];
    const float*  w      = (const float*)d_in[3];
    const float*  v      = (const float*)d_in[4];
    const float4* v4     = (const float4*)d_in[4];
    float* out = (float*)d_out;

    const size_t VH_B   = (size_t)VROWS * 640;                       // 16.65 MB
    const size_t U_OFF  = (VH_B + 255) & ~(size_t)255;
    const size_t U_B    = (size_t)VROWS * 16 * 4;                    // 1.66 MB
    const size_t NC_OFF = (U_OFF + U_B + 255) & ~(size_t)255;
    const size_t NC_B   = (size_t)VROWS * 4;                         // 104 KB
    const size_t PT_OFF = (NC_OFF + NC_B + 255) & ~(size_t)255;
    const size_t PT_B   = (size_t)NSLICE * BATCH * 4;                // 160 KB

    if (ws_size >= PT_OFF + PT_B) {
        unsigned* vh  = (unsigned*)d_ws;
        float*    u   = (float*)((char*)d_ws + U_OFF);
        float*    nc  = (float*)((char*)d_ws + NC_OFF);
        float*    prt = (float*)((char*)d_ws + PT_OFF);

        hipLaunchKernelGGL(ffm_prep, dim3((VROWS + 3) / 4), dim3(256), 0, stream,
                           v4, vh, u, nc);
        hipLaunchKernelGGL(ffm_sq, dim3(8 * 80), dim3(256), 0, stream,
                           dense, sparse, v, (const uint4*)vh, prt);
        hipLaunchKernelGGL(ffm_out, dim3(BATCH / 4), dim3(256), 0, stream,
                           dense, sparse, w0, w, u, nc, prt, out);
    } else {
        hipLaunchKernelGGL(ffm_fused, dim3(BATCH / 4), dim3(256), 0, stream,
                           dense, sparse, w0, w, v4, out);
    }
}

// Round 9
// 38.353 us; speedup vs baseline: 1.0503x; 1.0503x over previous
//
#include <hip/hip_runtime.h>

#define NDENSE 13
#define NSPARSE 26
#define ROW_F4 156     // fp32 v row = 156 float4
#define BATCH 4096
#define VROWS 26013
#define ROW_U32 160    // padded f8 row = 160 uint32 = 640 B = 5 x 128B slices
#define ROW_U4  40     // = 40 uint4
#define NSLICE 5       // 128 B f8 slices per row (8 fields each, slice 4 has 7+pad)
#define SRPB   32      // rows per block in sq kernel
#define RECW   32      // floats per packed row record: u[16], nrmc, w, pad -> 128 B

// ---------------- fp8 e4m3 (OCP) encode/decode --------------------------
#if defined(__has_builtin)
#if __has_builtin(__builtin_amdgcn_cvt_pk_fp8_f32) && __has_builtin(__builtin_amdgcn_cvt_pk_f32_fp8)
#define FP8_HW 1
#endif
#endif

typedef float f32x2 __attribute__((ext_vector_type(2)));

__device__ inline unsigned enc1(float f) {
    unsigned u = __float_as_uint(f);
    unsigned s = (u >> 24) & 0x80u;
    unsigned a = u & 0x7fffffffu;
    if (a >= 0x3c800000u) {                       // |f| >= 2^-6 : normal
        unsigned r = a + 0x7ffffu + ((a >> 20) & 1u);   // RNE at bit 20
        return s | ((r - (120u << 23)) >> 20);
    }
    return s | (unsigned)__float2uint_rn(__uint_as_float(a) * 512.f); // subnormal
}
__device__ inline float dec1(unsigned b) {
    unsigned em = b & 0x7fu;
    float mag = (em >= 8u) ? __uint_as_float((em << 20) + (120u << 23))
                           : (float)em * 0x1p-9f;
    return (b & 0x80u) ? -mag : mag;
}
__device__ inline unsigned enc4(float4 x) {
#ifdef FP8_HW
    int pk = 0;
    pk = __builtin_amdgcn_cvt_pk_fp8_f32(x.x, x.y, pk, false);
    pk = __builtin_amdgcn_cvt_pk_fp8_f32(x.z, x.w, pk, true);
    return (unsigned)pk;
#else
    return enc1(x.x) | (enc1(x.y) << 8) | (enc1(x.z) << 16) | (enc1(x.w) << 24);
#endif
}
__device__ inline float4 dec4(unsigned p) {
#ifdef FP8_HW
    f32x2 lo = __builtin_amdgcn_cvt_pk_f32_fp8((int)p, false);
    f32x2 hi = __builtin_amdgcn_cvt_pk_f32_fp8((int)p, true);
    return make_float4(lo.x, lo.y, hi.x, hi.y);
#else
    return make_float4(dec1(p & 0xffu), dec1((p >> 8) & 0xffu),
                       dec1((p >> 16) & 0xffu), dec1((p >> 24) & 0xffu));
#endif
}

// ---------------------------------------------------------------------------
// Prep: one pass over v. Emits (a) f8 copy (640 B rows, zero pad), (b) packed
// 128 B record per row: u[16] = sum_f v[r,f,:], nrmc = ||v||^2-||f8||^2, w[r].
__global__ __launch_bounds__(256) void ffm_prep(
    const float4* __restrict__ v4, const float* __restrict__ w,
    unsigned* __restrict__ vh, float* __restrict__ rec)
{
    const int wv = threadIdx.x >> 6, lane = threadIdx.x & 63;
    const int row = blockIdx.x * 4 + wv;
    if (row >= VROWS) return;

    float4 us = make_float4(0.f, 0.f, 0.f, 0.f);
    float  nc = 0.f;
#pragma unroll
    for (int p = 0; p < 3; ++p) {
        const int e4 = lane + 64 * p;
        if (e4 < ROW_F4) {
            const float4 x = v4[(size_t)row * ROW_F4 + e4];
            const unsigned pk = enc4(x);
            const float4 xh = dec4(pk);
            vh[(size_t)row * ROW_U32 + e4] = pk;
            us.x += x.x; us.y += x.y; us.z += x.z; us.w += x.w;
            nc += (x.x*x.x - xh.x*xh.x) + (x.y*x.y - xh.y*xh.y)
                + (x.z*x.z - xh.z*xh.z) + (x.w*x.w - xh.w*xh.w);
        } else if (e4 < ROW_U32) {
            vh[(size_t)row * ROW_U32 + e4] = 0u;   // pad = 0
        }
    }
    // k-group = e4&3 = lane&3 (invariant under +64)
#pragma unroll
    for (int m = 4; m <= 32; m <<= 1) {
        us.x += __shfl_xor(us.x, m); us.y += __shfl_xor(us.y, m);
        us.z += __shfl_xor(us.z, m); us.w += __shfl_xor(us.w, m);
    }
    float* r = rec + (size_t)row * RECW;
    if (lane < 4) ((float4*)r)[lane] = us;
#pragma unroll
    for (int m = 1; m <= 32; m <<= 1) nc += __shfl_xor(nc, m);
    if (lane == 0) { r[16] = nc; r[17] = w[row]; }
}

// ---------------------------------------------------------------------------
// sq kernel: 128 B f8 slices (line-exact), XCD-pinned (<=2 slices/XCD).
// Slice s covers fields 8s..8s+7; lane owns (row, one field vector = 16 B).
// Dense contribution exact fp32 from LDS. Writes per-slice sq partials.
__global__ __launch_bounds__(256) void ffm_sq(
    const float* __restrict__ dense,
    const int*   __restrict__ sparse,
    const float4* __restrict__ v4,
    const uint4* __restrict__ vh4,
    float*       __restrict__ part)     // [5][4096]
{
    const int x = blockIdx.x & 7;
    const int i = blockIdx.x >> 3;       // 0..79 per XCD
    const int fid = x * 80 + i;          // 0..639
    const int slice = fid >> 7, chunk = fid & 127;
    const int row0 = chunk * SRPB;

    __shared__ int    vrow_s[SRPB * NSPARSE];  // 3328 B
    __shared__ float  dsh   [SRPB * NDENSE];   // 1664 B
    __shared__ float4 vsh4  [NDENSE * 32];     // 6656 B fp32 dense v-slice

    const int t = threadIdx.x;
    for (int q = t; q < SRPB * NSPARSE; q += 256) {
        const int r = q / NSPARSE, j = q % NSPARSE;
        vrow_s[q] = sparse[(row0 + r) * NSPARSE + j] + NDENSE + 1000 * j;
    }
    for (int q = t; q < SRPB * NDENSE; q += 256)
        dsh[q] = dense[row0 * NDENSE + q];
    for (int q = t; q < NDENSE * 32; q += 256) {
        const int d = q >> 5, idx = q & 31;          // f4 col = 32*slice + idx
        vsh4[q] = (32 * slice + idx < ROW_F4)
                  ? v4[(size_t)d * ROW_F4 + 32 * slice + idx]
                  : make_float4(0.f, 0.f, 0.f, 0.f);
    }
    __syncthreads();

    const int lane = t & 63, wv = t >> 6;
    const int rl = wv * 8 + (lane >> 3);   // local row 0..31
    const int c  = lane & 7;               // field within slice

    float4 a0 = make_float4(0.f,0.f,0.f,0.f), a1 = a0, a2 = a0, a3 = a0;

    // dense contribution (exact fp32): field 8*slice + c
#pragma unroll
    for (int d = 0; d < NDENSE; ++d) {
        const float wg = dsh[rl * NDENSE + d];
        const float4 b0 = vsh4[d * 32 + c * 4 + 0];
        const float4 b1 = vsh4[d * 32 + c * 4 + 1];
        const float4 b2 = vsh4[d * 32 + c * 4 + 2];
        const float4 b3 = vsh4[d * 32 + c * 4 + 3];
        a0.x += wg*b0.x; a0.y += wg*b0.y; a0.z += wg*b0.z; a0.w += wg*b0.w;
        a1.x += wg*b1.x; a1.y += wg*b1.y; a1.z += wg*b1.z; a1.w += wg*b1.w;
        a2.x += wg*b2.x; a2.y += wg*b2.y; a2.z += wg*b2.z; a2.w += wg*b2.w;
        a3.x += wg*b3.x; a3.y += wg*b3.y; a3.z += wg*b3.z; a3.w += wg*b3.w;
    }

    // 26 f8 gathers: 16 B each = one complete field vector (8 lanes = 128 B line)
#pragma unroll
    for (int j = 0; j < NSPARSE; ++j) {
        const unsigned r = (unsigned)vrow_s[rl * NSPARSE + j];
        const uint4 g = vh4[(size_t)r * ROW_U4 + slice * 8 + c];
        const float4 d0 = dec4(g.x), d1 = dec4(g.y), d2 = dec4(g.z), d3 = dec4(g.w);
        a0.x += d0.x; a0.y += d0.y; a0.z += d0.z; a0.w += d0.w;
        a1.x += d1.x; a1.y += d1.y; a1.z += d1.z; a1.w += d1.w;
        a2.x += d2.x; a2.y += d2.y; a2.z += d2.z; a2.w += d2.w;
        a3.x += d3.x; a3.y += d3.y; a3.z += d3.z; a3.w += d3.w;
    }

    float sq = a0.x*a0.x + a0.y*a0.y + a0.z*a0.z + a0.w*a0.w
             + a1.x*a1.x + a1.y*a1.y + a1.z*a1.z + a1.w*a1.w
             + a2.x*a2.x + a2.y*a2.y + a2.z*a2.z + a2.w*a2.w
             + a3.x*a3.x + a3.y*a3.y + a3.z*a3.z + a3.w*a3.w;
    sq += __shfl_xor(sq, 1);
    sq += __shfl_xor(sq, 2);
    sq += __shfl_xor(sq, 4);
    if (c == 0) part[slice * BATCH + row0 + rl] = sq;
}

// ---------------------------------------------------------------------------
// Final: exact s from packed records (1 line per gather), sq = partials +
// diagonal correction, first order. One wave per batch row.
__global__ __launch_bounds__(256) void ffm_out(
    const float* __restrict__ dense,
    const int*   __restrict__ sparse,
    const float* __restrict__ w0,
    const float* __restrict__ rec,
    const float* __restrict__ part,
    float*       __restrict__ out)
{
    const int wave = threadIdx.x >> 6;
    const int lane = threadIdx.x & 63;
    const int b = blockIdx.x * 4 + wave;
    const int g = lane >> 4, k = lane & 15;

    // exact first moment s[k]
    float s = 0.f;
    for (int j = g; j < NSPARSE; j += 4) {
        const int r = sparse[b * NSPARSE + j] + NDENSE + 1000 * j;
        s += rec[(size_t)r * RECW + k];
    }
    for (int d = g; d < NDENSE; d += 4)
        s += dense[b * NDENSE + d] * rec[(size_t)d * RECW + k];
    s += __shfl_xor(s, 16);
    s += __shfl_xor(s, 32);          // lanes with same k hold total s[k]

    float s2 = s * s;
    s2 += __shfl_xor(s2, 1);
    s2 += __shfl_xor(s2, 2);
    s2 += __shfl_xor(s2, 4);
    s2 += __shfl_xor(s2, 8);         // ||s||^2 in every lane

    float red = 0.f, fo = 0.f;
    if (lane < NSLICE) red = part[lane * BATCH + b];
    if (lane < NSPARSE) {
        const int r = sparse[b * NSPARSE + lane] + NDENSE + 1000 * lane;
        red += rec[(size_t)r * RECW + 16];   // diagonal correction (same line as u)
        fo   = rec[(size_t)r * RECW + 17];   // w[r] (same line)
    }
    if (lane < NDENSE) fo += dense[b * NDENSE + lane] * rec[(size_t)lane * RECW + 17];
#pragma unroll
    for (int m = 1; m <= 32; m <<= 1) {
        fo  += __shfl_xor(fo, m);
        red += __shfl_xor(red, m);
    }
    if (lane == 0) out[b] = w0[0] + fo + 0.5f * (s2 - red);
}

// ---------------------------------------------------------------------------
// Fallback: R1 fused kernel (only if ws too small).
__global__ __launch_bounds__(256) void ffm_fused(
    const float* __restrict__ dense, const int* __restrict__ sparse,
    const float* __restrict__ w0, const float* __restrict__ w,
    const float4* __restrict__ v4, float* __restrict__ out)
{
    const int wave = threadIdx.x >> 6;
    const int lane = threadIdx.x & 63;
    const int b = blockIdx.x * 4 + wave;

    float dv[NDENSE];
#pragma unroll
    for (int d = 0; d < NDENSE; ++d) dv[d] = dense[b * NDENSE + d];
    int myidx = 0;
    if (lane < NSPARSE) myidx = sparse[b * NSPARSE + lane] + NDENSE + 1000 * lane;

    float4 s = make_float4(0.f, 0.f, 0.f, 0.f);
    float  sq = 0.f;
#pragma unroll
    for (int p = 0; p < 3; ++p) {
        const int e4 = lane + 64 * p;
        if (e4 < ROW_F4) {
            float4 acc = make_float4(0.f, 0.f, 0.f, 0.f);
#pragma unroll
            for (int d = 0; d < NDENSE; ++d) {
                const float4 vv = v4[d * ROW_F4 + e4];
                acc.x += dv[d]*vv.x; acc.y += dv[d]*vv.y;
                acc.z += dv[d]*vv.z; acc.w += dv[d]*vv.w;
            }
#pragma unroll
            for (int j = 0; j < NSPARSE; ++j) {
                const int ij = __shfl(myidx, j);
                const float4 vv = v4[(size_t)ij * ROW_F4 + e4];
                acc.x += vv.x; acc.y += vv.y; acc.z += vv.z; acc.w += vv.w;
            }
            s.x += acc.x; s.y += acc.y; s.z += acc.z; s.w += acc.w;
            sq  += acc.x*acc.x + acc.y*acc.y + acc.z*acc.z + acc.w*acc.w;
        }
    }
#pragma unroll
    for (int m = 4; m <= 32; m <<= 1) {
        s.x += __shfl_xor(s.x, m); s.y += __shfl_xor(s.y, m);
        s.z += __shfl_xor(s.z, m); s.w += __shfl_xor(s.w, m);
    }
    float s2 = s.x*s.x + s.y*s.y + s.z*s.z + s.w*s.w;
    s2 += __shfl_xor(s2, 1);
    s2 += __shfl_xor(s2, 2);
#pragma unroll
    for (int m = 1; m <= 32; m <<= 1) sq += __shfl_xor(sq, m);
    float fo = 0.f;
    if (lane < NSPARSE) fo = w[myidx];
    if (lane < NDENSE)  fo += dense[b * NDENSE + lane] * w[lane];
#pragma unroll
    for (int m = 1; m <= 32; m <<= 1) fo += __shfl_xor(fo, m);
    if (lane == 0) out[b] = w0[0] + fo + 0.5f * (s2 - sq);
}

extern "C" void kernel_launch(void* const* d_in, const int* in_sizes, int n_in,
                              void* d_out, int out_size, void* d_ws, size_t ws_size,
                              hipStream_t stream) {
    const float*  dense  = (const float*)d_in[0];
    const int*    sparse = (const int*)d_in[1];
    const float*  w0     = (const float*)d_in[2];
    const float*  w      = (const float*)d_in[3];
    const float4* v4     = (const float4*)d_in[4];
    float* out = (float*)d_out;

    const size_t VH_B   = (size_t)VROWS * 640;                       // 16.65 MB
    const size_t RC_OFF = (VH_B + 255) & ~(size_t)255;
    const size_t RC_B   = (size_t)VROWS * RECW * 4;                  // 3.33 MB
    const size_t PT_OFF = (RC_OFF + RC_B + 255) & ~(size_t)255;
    const size_t PT_B   = (size_t)NSLICE * BATCH * 4;                // 80 KB

    if (ws_size >= PT_OFF + PT_B) {
        unsigned* vh  = (unsigned*)d_ws;
        float*    rc  = (float*)((char*)d_ws + RC_OFF);
        float*    prt = (float*)((char*)d_ws + PT_OFF);

        hipLaunchKernelGGL(ffm_prep, dim3((VROWS + 3) / 4), dim3(256), 0, stream,
                           v4, w, vh, rc);
        hipLaunchKernelGGL(ffm_sq, dim3(8 * 80), dim3(256), 0, stream,
                           dense, sparse, v4, (const uint4*)vh, prt);
        hipLaunchKernelGGL(ffm_out, dim3(BATCH / 4), dim3(256), 0, stream,
                           dense, sparse, w0, rc, prt, out);
    } else {
        hipLaunchKernelGGL(ffm_fused, dim3(BATCH / 4), dim3(256), 0, stream,
                           dense, sparse, w0, w, v4, out);
    }
}